// Round 1
// baseline (1711.184 us; speedup 1.0000x reference)
//
#include <hip/hip_runtime.h>
#include <math.h>

// Dimensions (fixed by the problem)
// B=128, S=256, G=8, CMAX=6, T=32, E=64, NH=4, dh=16, L=2, DFF=256, Z=3

__device__ __forceinline__ bool is_masked(const void* mask_, int flag, int idx) {
  return flag ? (((const unsigned char*)mask_)[idx] != 0)
              : (((const int*)mask_)[idx] != 0);
}

// Detect whether the bool `mask` input arrived as int32 (flag=0) or packed bytes (flag=1).
__global__ void detect_mask_kernel(const unsigned int* __restrict__ mask_words,
                                   int* __restrict__ flag) {
  __shared__ int sh;
  if (threadIdx.x == 0) sh = 0;
  __syncthreads();
  int bad = 0;
  for (int i = threadIdx.x; i < 8192; i += 256)
    if (mask_words[i] > 1u) bad = 1;
  if (bad) atomicOr(&sh, 1);
  __syncthreads();
  if (threadIdx.x == 0) *flag = sh;
}

// Per-token conv encoder: conv1(6->32,k5,p2)+relu -> conv2(32->64,k3,p1)+relu -> mean_T
// Only the selected expert (shank id) is computed; masked tokens skip conv.
// Then emb += shank_emb[sid] + positional encoding.
__global__ __launch_bounds__(128) void conv_emb_kernel(
    const float* __restrict__ wav, const int* __restrict__ sid_,
    const void* __restrict__ mask_, const int* __restrict__ flagp,
    const float* __restrict__ w1_, const float* __restrict__ b1_,
    const float* __restrict__ w2_, const float* __restrict__ b2_,
    const float* __restrict__ shank_emb, float* __restrict__ hout) {
  __shared__ float xp[6][36];      // input padded by 2 each side
  __shared__ float w1s[960];       // [32][6][5]
  __shared__ float b1s[32];
  __shared__ float b2s[64];
  __shared__ float h1p[32][34];    // conv1 out, padded by 1 each side
  __shared__ float w2t[96][65];    // transposed conv2 weights [ic*3+k][e], +1 pad
  __shared__ float partial[64][2];
  int n = blockIdx.x;
  int tid = threadIdx.x;
  int g = sid_[n];
  int flag = *flagp;
  bool masked = is_masked(mask_, flag, n);
  if (!masked) {
    for (int i = tid; i < 6 * 36; i += 128) {
      int ic = i / 36, t = i % 36;
      xp[ic][t] = (t >= 2 && t < 34) ? wav[n * 192 + ic * 32 + (t - 2)] : 0.f;
    }
    for (int i = tid; i < 960; i += 128) w1s[i] = w1_[g * 960 + i];
    if (tid < 32) b1s[tid] = b1_[g * 32 + tid];
    if (tid < 64) b2s[tid] = b2_[g * 64 + tid];
    for (int i = tid; i < 6144; i += 128) {
      int e = i / 96, r = i % 96;
      w2t[r][e] = w2_[g * 6144 + i];
    }
    if (tid < 32) { h1p[tid][0] = 0.f; h1p[tid][33] = 0.f; }
    __syncthreads();
    // conv1: 32 oc x 32 t outputs
    for (int i = tid; i < 1024; i += 128) {
      int oc = i >> 5, t = i & 31;
      float acc = b1s[oc];
#pragma unroll
      for (int ic = 0; ic < 6; ic++)
#pragma unroll
        for (int kk = 0; kk < 5; kk++)
          acc += xp[ic][t + kk] * w1s[oc * 30 + ic * 5 + kk];
      h1p[oc][t + 1] = fmaxf(acc, 0.f);
    }
    __syncthreads();
    // conv2: thread (e, half) computes out channel e over 16 t's
    {
      int e = tid & 63, half = tid >> 6, t0 = half * 16;
      float bb = b2s[e];
      float acc[16];
#pragma unroll
      for (int t = 0; t < 16; t++) acc[t] = bb;
      for (int ic = 0; ic < 32; ic++) {
#pragma unroll
        for (int kk = 0; kk < 3; kk++) {
          float w = w2t[ic * 3 + kk][e];
#pragma unroll
          for (int t = 0; t < 16; t++)
            acc[t] += h1p[ic][t0 + t + kk] * w;
        }
      }
      float sum = 0.f;
#pragma unroll
      for (int t = 0; t < 16; t++) sum += fmaxf(acc[t], 0.f);
      partial[e][half] = sum;
    }
  }
  __syncthreads();
  if (tid < 64) {
    int e = tid, s = n & 255;
    float conv = masked ? 0.f : (partial[e][0] + partial[e][1]) * (1.f / 32.f);
    float div = __expf(-(float)(e & ~1) * (9.21034037f / 64.f));  // ln(10000)/64
    float angle = (float)s * div;
    float pe = (e & 1) ? cosf(angle) : sinf(angle);
    hout[n * 64 + e] = conv + shank_emb[g * 64 + e] + pe;
  }
}

// qkv projection: [32768,64] @ [192,64]^T + b, scattered into q/k/v [B,NH,S,16]
__global__ __launch_bounds__(256) void qkv_kernel(
    const float* __restrict__ h, const float* __restrict__ W,
    const float* __restrict__ bias, float* __restrict__ q,
    float* __restrict__ k, float* __restrict__ v) {
  __shared__ float hs[32][64];
  int n0 = blockIdx.x * 32;
  for (int i = threadIdx.x; i < 2048; i += 256) hs[i >> 6][i & 63] = h[n0 * 64 + i];
  __syncthreads();
  for (int t = threadIdx.x; t < 32 * 192; t += 256) {
    int row = t / 192, c = t % 192;
    const float* wr = W + c * 64;
    float acc = bias[c];
#pragma unroll
    for (int j = 0; j < 64; j++) acc += hs[row][j] * wr[j];
    int n = n0 + row;
    int b_ = n >> 8, s = n & 255;
    int which = c >> 6, cc = c & 63, hd = cc >> 4, d = cc & 15;
    float* dst = (which == 0) ? q : (which == 1) ? k : v;
    dst[(((b_ * 4 + hd) * 256) + s) * 16 + d] = acc;
  }
}

// attention: one block per (b, head); one thread per query row; online softmax
__global__ __launch_bounds__(256) void attn_kernel(
    const float* __restrict__ q, const float* __restrict__ k,
    const float* __restrict__ v, const void* __restrict__ mask_,
    const int* __restrict__ flagp, float* __restrict__ o) {
  __shared__ float ks[256][16];
  __shared__ float vs[256][16];
  __shared__ float bias[256];
  int bh = blockIdx.x;
  int b_ = bh >> 2, hd = bh & 3;
  int tid = threadIdx.x;
  const float* kbase = k + bh * 4096;
  const float* vbase = v + bh * 4096;
  for (int i = tid; i < 4096; i += 256) {
    ks[i >> 4][i & 15] = kbase[i];
    vs[i >> 4][i & 15] = vbase[i];
  }
  int flag = *flagp;
  bias[tid] = is_masked(mask_, flag, b_ * 256 + tid) ? -1e9f : 0.f;
  __syncthreads();
  float qv[16];
  const float* qbase = q + (bh * 256 + tid) * 16;
#pragma unroll
  for (int d = 0; d < 16; d++) qv[d] = qbase[d] * 0.25f;  // 1/sqrt(16)
  float m = -1e30f, l = 0.f;
  float acc[16];
#pragma unroll
  for (int d = 0; d < 16; d++) acc[d] = 0.f;
  for (int kk = 0; kk < 256; kk++) {
    float sc = bias[kk];
#pragma unroll
    for (int d = 0; d < 16; d++) sc += qv[d] * ks[kk][d];
    float mn = fmaxf(m, sc);
    float alpha = __expf(m - mn);
    float pp = __expf(sc - mn);
    l = l * alpha + pp;
#pragma unroll
    for (int d = 0; d < 16; d++) acc[d] = acc[d] * alpha + pp * vs[kk][d];
    m = mn;
  }
  float inv = 1.f / l;
  float* ob = o + (b_ * 256 + tid) * 64 + hd * 16;
#pragma unroll
  for (int d = 0; d < 16; d++) ob[d] = acc[d] * inv;
}

// out_proj + residual + LayerNorm. 4 rows/block, one wave per row.
__global__ __launch_bounds__(256) void outproj_ln_kernel(
    const float* __restrict__ o, const float* __restrict__ W,
    const float* __restrict__ bias, const float* __restrict__ gg,
    const float* __restrict__ bb, float* __restrict__ h) {
  __shared__ float os[4][64];
  int wv = threadIdx.x >> 6, e = threadIdx.x & 63;
  int n = blockIdx.x * 4 + wv;
  os[wv][e] = o[n * 64 + e];
  __syncthreads();
  float acc = bias[e];
  const float* wr = W + e * 64;
#pragma unroll
  for (int j = 0; j < 64; j++) acc += os[wv][j] * wr[j];
  float r = h[n * 64 + e] + acc;
  float sum = r;
#pragma unroll
  for (int off = 32; off; off >>= 1) sum += __shfl_xor(sum, off);
  float mean = sum * (1.f / 64.f);
  float dd = r - mean;
  float vsum = dd * dd;
#pragma unroll
  for (int off = 32; off; off >>= 1) vsum += __shfl_xor(vsum, off);
  float var = vsum * (1.f / 64.f);
  h[n * 64 + e] = dd * rsqrtf(var + 1e-5f) * gg[e] + bb[e];
}

// ff1: [32768,64] -> [32768,256], relu
__global__ __launch_bounds__(256) void ff1_kernel(
    const float* __restrict__ h, const float* __restrict__ W,
    const float* __restrict__ bias, float* __restrict__ out) {
  __shared__ float hs[32][64];
  int n0 = blockIdx.x * 32;
  for (int i = threadIdx.x; i < 2048; i += 256) hs[i >> 6][i & 63] = h[n0 * 64 + i];
  __syncthreads();
  for (int t = threadIdx.x; t < 32 * 256; t += 256) {
    int row = t >> 8, c = t & 255;
    const float* wr = W + c * 64;
    float acc = bias[c];
#pragma unroll
    for (int j = 0; j < 64; j++) acc += hs[row][j] * wr[j];
    out[(n0 + row) * 256 + c] = fmaxf(acc, 0.f);
  }
}

// ff2 + residual + LayerNorm. 4 rows/block, one wave per row.
__global__ __launch_bounds__(256) void ff2_ln_kernel(
    const float* __restrict__ ffin, const float* __restrict__ W,
    const float* __restrict__ bias, const float* __restrict__ gg,
    const float* __restrict__ bb, float* __restrict__ h) {
  __shared__ float fs[4][256];
  int wv = threadIdx.x >> 6, e = threadIdx.x & 63;
  int n = blockIdx.x * 4 + wv;
#pragma unroll
  for (int jj = 0; jj < 4; jj++) fs[wv][e + jj * 64] = ffin[n * 256 + e + jj * 64];
  __syncthreads();
  float acc = bias[e];
  const float* wr = W + e * 256;
  for (int j = 0; j < 256; j++) acc += fs[wv][j] * wr[j];
  float r = h[n * 64 + e] + acc;
  float sum = r;
#pragma unroll
  for (int off = 32; off; off >>= 1) sum += __shfl_xor(sum, off);
  float mean = sum * (1.f / 64.f);
  float dd = r - mean;
  float vsum = dd * dd;
#pragma unroll
  for (int off = 32; off; off >>= 1) vsum += __shfl_xor(vsum, off);
  float var = vsum * (1.f / 64.f);
  h[n * 64 + e] = dd * rsqrtf(var + 1e-5f) * gg[e] + bb[e];
}

// masked mean pool over S
__global__ __launch_bounds__(64) void pool_kernel(
    const float* __restrict__ h, const void* __restrict__ mask_,
    const int* __restrict__ flagp, float* __restrict__ pooled) {
  int b = blockIdx.x, e = threadIdx.x;
  int flag = *flagp;
  float sum = 0.f, cnt = 0.f;
  for (int s = 0; s < 256; s++) {
    if (!is_masked(mask_, flag, b * 256 + s)) {
      sum += h[(b * 256 + s) * 64 + e];
      cnt += 1.f;
    }
  }
  pooled[b * 64 + e] = sum / (cnt + 1e-8f);
}

// all heads fused: cls (3), mus (Z*2), sigmas (Z*2), d (1) -> 16 outputs per b
__global__ __launch_bounds__(64) void heads_kernel(
    const float* __restrict__ pooled,
    const float* __restrict__ cls_w1, const float* __restrict__ cls_b1,
    const float* __restrict__ cls_w2, const float* __restrict__ cls_b2,
    const float* __restrict__ mu_w1, const float* __restrict__ mu_b1,
    const float* __restrict__ mu_w2, const float* __restrict__ mu_b2,
    const float* __restrict__ ls_w1, const float* __restrict__ ls_b1,
    const float* __restrict__ ls_w2, const float* __restrict__ ls_b2,
    const float* __restrict__ d_w1, const float* __restrict__ d_b1,
    const float* __restrict__ d_w2, const float* __restrict__ d_b2,
    float* __restrict__ out) {
  int b = blockIdx.x, e = threadIdx.x;
  __shared__ float p[64];
  __shared__ float t1[64];
  p[e] = pooled[b * 64 + e];
  __syncthreads();
  // cls head
  {
    float a = cls_b1[e];
    for (int j = 0; j < 64; j++) a += p[j] * cls_w1[e * 64 + j];
    t1[e] = fmaxf(a, 0.f);
  }
  __syncthreads();
  if (e < 3) {
    float a2 = cls_b2[e];
    for (int j = 0; j < 64; j++) a2 += t1[j] * cls_w2[e * 64 + j];
    out[b * 16 + e] = a2;
  }
  // mu / sigma heads (Z=3)
  for (int z = 0; z < 3; z++) {
    __syncthreads();
    {
      float a = mu_b1[z * 64 + e];
      for (int j = 0; j < 64; j++) a += p[j] * mu_w1[(z * 64 + e) * 64 + j];
      t1[e] = fmaxf(a, 0.f);
    }
    __syncthreads();
    if (e < 2) {
      float a2 = mu_b2[z * 2 + e];
      for (int j = 0; j < 64; j++) a2 += t1[j] * mu_w2[(z * 2 + e) * 64 + j];
      out[b * 16 + 3 + z * 2 + e] = a2;
    }
    __syncthreads();
    {
      float a = ls_b1[z * 64 + e];
      for (int j = 0; j < 64; j++) a += p[j] * ls_w1[(z * 64 + e) * 64 + j];
      t1[e] = fmaxf(a, 0.f);
    }
    __syncthreads();
    if (e < 2) {
      float a2 = ls_b2[z * 2 + e];
      for (int j = 0; j < 64; j++) a2 += t1[j] * ls_w2[(z * 2 + e) * 64 + j];
      out[b * 16 + 9 + z * 2 + e] = __expf(a2);
    }
  }
  // depth head
  __syncthreads();
  {
    float a = d_b1[e];
    for (int j = 0; j < 64; j++) a += p[j] * d_w1[e * 64 + j];
    t1[e] = fmaxf(a, 0.f);
  }
  __syncthreads();
  if (e == 0) {
    float a2 = d_b2[0];
    for (int j = 0; j < 64; j++) a2 += t1[j] * d_w2[j];
    out[b * 16 + 15] = 1.f / (1.f + __expf(-a2));
  }
}

extern "C" void kernel_launch(void* const* d_in, const int* in_sizes, int n_in,
                              void* d_out, int out_size, void* d_ws, size_t ws_size,
                              hipStream_t stream) {
  const float* wav       = (const float*)d_in[0];
  const int*   sid       = (const int*)d_in[1];
  const void*  mask      = d_in[2];
  const float* conv1_w   = (const float*)d_in[3];
  const float* conv1_b   = (const float*)d_in[4];
  const float* conv2_w   = (const float*)d_in[5];
  const float* conv2_b   = (const float*)d_in[6];
  const float* shank_emb = (const float*)d_in[7];
  const float* in_proj_w = (const float*)d_in[8];
  const float* in_proj_b = (const float*)d_in[9];
  const float* out_proj_w= (const float*)d_in[10];
  const float* out_proj_b= (const float*)d_in[11];
  const float* ln1_g     = (const float*)d_in[12];
  const float* ln1_b     = (const float*)d_in[13];
  const float* ff1_w     = (const float*)d_in[14];
  const float* ff1_b     = (const float*)d_in[15];
  const float* ff2_w     = (const float*)d_in[16];
  const float* ff2_b     = (const float*)d_in[17];
  const float* ln2_g     = (const float*)d_in[18];
  const float* ln2_b     = (const float*)d_in[19];
  const float* cls_w1    = (const float*)d_in[20];
  const float* cls_b1    = (const float*)d_in[21];
  const float* cls_w2    = (const float*)d_in[22];
  const float* cls_b2    = (const float*)d_in[23];
  const float* mu_w1     = (const float*)d_in[24];
  const float* mu_b1     = (const float*)d_in[25];
  const float* mu_w2     = (const float*)d_in[26];
  const float* mu_b2     = (const float*)d_in[27];
  const float* ls_w1     = (const float*)d_in[28];
  const float* ls_b1     = (const float*)d_in[29];
  const float* ls_w2     = (const float*)d_in[30];
  const float* ls_b2     = (const float*)d_in[31];
  const float* d_w1      = (const float*)d_in[32];
  const float* d_b1      = (const float*)d_in[33];
  const float* d_w2      = (const float*)d_in[34];
  const float* d_b2      = (const float*)d_in[35];
  float* out = (float*)d_out;

  float* ws    = (float*)d_ws;
  float* h     = ws;                 // [32768,64]
  float* q     = ws + 2097152;       // [B,NH,S,16]
  float* kbuf  = ws + 4194304;
  float* vbuf  = ws + 6291456;
  float* obuf  = ws + 8388608;       // [32768,64]
  float* ff    = ws + 2097152;       // [32768,256], aliases dead q/k/v/o
  float* pooled= ws + 10485760;      // [128,64]
  int*   flag  = (int*)(ws + 10485760 + 8192);

  detect_mask_kernel<<<1, 256, 0, stream>>>((const unsigned int*)mask, flag);
  conv_emb_kernel<<<32768, 128, 0, stream>>>(wav, sid, mask, flag, conv1_w, conv1_b,
                                             conv2_w, conv2_b, shank_emb, h);
  for (int l = 0; l < 2; l++) {
    qkv_kernel<<<1024, 256, 0, stream>>>(h, in_proj_w + l * 12288, in_proj_b + l * 192,
                                         q, kbuf, vbuf);
    attn_kernel<<<512, 256, 0, stream>>>(q, kbuf, vbuf, mask, flag, obuf);
    outproj_ln_kernel<<<8192, 256, 0, stream>>>(obuf, out_proj_w + l * 4096,
                                                out_proj_b + l * 64, ln1_g + l * 64,
                                                ln1_b + l * 64, h);
    ff1_kernel<<<1024, 256, 0, stream>>>(h, ff1_w + l * 16384, ff1_b + l * 256, ff);
    ff2_ln_kernel<<<8192, 256, 0, stream>>>(ff, ff2_w + l * 16384, ff2_b + l * 64,
                                            ln2_g + l * 64, ln2_b + l * 64, h);
  }
  pool_kernel<<<128, 64, 0, stream>>>(h, mask, flag, pooled);
  heads_kernel<<<128, 64, 0, stream>>>(pooled, cls_w1, cls_b1, cls_w2, cls_b2,
                                       mu_w1, mu_b1, mu_w2, mu_b2,
                                       ls_w1, ls_b1, ls_w2, ls_b2,
                                       d_w1, d_b1, d_w2, d_b2, out);
}

// Round 2
// 910.542 us; speedup vs baseline: 1.8793x; 1.8793x over previous
//
#include <hip/hip_runtime.h>
#include <math.h>

// B=128, S=256, G=8, CMAX=6, T=32, E=64, NH=4, dh=16, L=2, DFF=256, Z=3

__device__ __forceinline__ bool is_masked(const void* mask_, int flag, int idx) {
  return flag ? (((const unsigned char*)mask_)[idx] != 0)
              : (((const int*)mask_)[idx] != 0);
}

__device__ __forceinline__ void ld4(const float* p, float* dst) {
  float4 t = *reinterpret_cast<const float4*>(p);
  dst[0] = t.x; dst[1] = t.y; dst[2] = t.z; dst[3] = t.w;
}

// Detect mask dtype (int32 vs byte-packed bool); zero counters.
__global__ void detect_mask_kernel(const unsigned int* __restrict__ mw,
                                   int* __restrict__ flag, int* __restrict__ counts,
                                   int* __restrict__ lens) {
  __shared__ int sh;
  if (threadIdx.x == 0) sh = 0;
  __syncthreads();
  int bad = 0;
  for (int i = threadIdx.x; i < 8192; i += 256)
    if (mw[i] > 1u) bad = 1;
  if (bad) atomicOr(&sh, 1);
  if (threadIdx.x < 8) counts[threadIdx.x] = 0;
  if (threadIdx.x < 128) lens[threadIdx.x] = 0;
  __syncthreads();
  if (threadIdx.x == 0) *flag = sh;
}

// Bin active tokens by shank id; count active tokens per batch (mask is a suffix).
__global__ void bin_kernel(const int* __restrict__ sid, const void* __restrict__ mask_,
                           const int* __restrict__ flagp, int* __restrict__ counts,
                           int* __restrict__ lens, int* __restrict__ idxbuf) {
  int n = blockIdx.x * 256 + threadIdx.x;
  int flag = *flagp;
  if (!is_masked(mask_, flag, n)) {
    int g = sid[n];
    int pos = atomicAdd(&counts[g], 1);
    idxbuf[g * 32768 + pos] = n;
    atomicAdd(&lens[n >> 8], 1);
  }
}

// Base embedding: shank_emb[sid] + positional encoding (masked tokens get only this).
__global__ __launch_bounds__(256) void init_emb_kernel(
    const int* __restrict__ sid, const float* __restrict__ shank_emb,
    float* __restrict__ hout) {
  int i = blockIdx.x * 256 + threadIdx.x;
  int n = i >> 6, e = i & 63, s = n & 255;
  int g = sid[n];
  float div = __expf(-(float)(e & ~1) * (9.21034037f / 64.f));
  float angle = (float)s * div;
  float pe = (e & 1) ? cosf(angle) : sinf(angle);
  hout[i] = shank_emb[g * 64 + e] + pe;
}

// Conv encoder, weights resident per block: each block owns one expert g and
// loops over its binned tokens, 4 tokens per iteration.
#define CONV_BPG 96
__global__ __launch_bounds__(256, 3) void conv_kernel(
    const int* __restrict__ idxbuf, const int* __restrict__ counts,
    const float* __restrict__ wav,
    const float* __restrict__ w1_, const float* __restrict__ b1_,
    const float* __restrict__ w2_, const float* __restrict__ b2_,
    float* __restrict__ hout) {
  __shared__ __align__(16) float w1p[32][33];   // [oc][ic*5+kk], +1 pad
  __shared__ float b1s[32];
  __shared__ float b2s[64];
  __shared__ __align__(16) float w2t[96][65];   // [ic*3+kk][e], +1 pad
  __shared__ __align__(16) float xp[4][6][36];  // 16B-aligned rows (36*4=144)
  __shared__ __align__(16) float h1p[4][32][36];
  int g = blockIdx.x & 7;
  int bib = blockIdx.x >> 3;
  int tid = threadIdx.x;
  for (int i = tid; i < 960; i += 256) { int oc = i / 30, r = i % 30; w1p[oc][r] = w1_[g * 960 + i]; }
  if (tid < 32) b1s[tid] = b1_[g * 32 + tid];
  if (tid < 64) b2s[tid] = b2_[g * 64 + tid];
  for (int i = tid; i < 6144; i += 256) { int e = i / 96, r = i % 96; w2t[r][e] = w2_[g * 6144 + i]; }
  int cnt = counts[g];
  for (int base = bib * 4; base < cnt; base += CONV_BPG * 4) {
    __syncthreads();
    // stage up to 4 tokens' waveforms, zero-padded by 2 each side
    for (int i = tid; i < 4 * 6 * 36; i += 256) {
      int tok = i / 216, rem = i % 216, ic = rem / 36, t = rem % 36;
      float v = 0.f;
      int ti = base + tok;
      if (ti < cnt && t >= 2 && t < 34) {
        int n = idxbuf[g * 32768 + ti];
        v = wav[n * 192 + ic * 32 + (t - 2)];
      }
      xp[tok][ic][t] = v;
    }
    __syncthreads();
    // conv1: thread = (tok, oc, half); 16 consecutive t's each
    {
      int tok = tid >> 6, rest = tid & 63, oc = rest >> 1, half = rest & 1;
      int t0 = half * 16;
      float o[16];
      float bb = b1s[oc];
#pragma unroll
      for (int t = 0; t < 16; t++) o[t] = bb;
#pragma unroll
      for (int ic = 0; ic < 6; ic++) {
        float xv[20];
#pragma unroll
        for (int q = 0; q < 5; q++) ld4(&xp[tok][ic][t0 + 4 * q], &xv[4 * q]);
#pragma unroll
        for (int kk = 0; kk < 5; kk++) {
          float w = w1p[oc][ic * 5 + kk];
#pragma unroll
          for (int t = 0; t < 16; t++) o[t] += xv[t + kk] * w;
        }
      }
      if (half == 0) {
        h1p[tok][oc][0] = 0.f;
      } else {
        h1p[tok][oc][33] = 0.f; h1p[tok][oc][34] = 0.f; h1p[tok][oc][35] = 0.f;
      }
#pragma unroll
      for (int t = 0; t < 16; t++) h1p[tok][oc][1 + t0 + t] = fmaxf(o[t], 0.f);
    }
    __syncthreads();
    // conv2: thread = (tok, e); 32 t accumulators in regs
    {
      int tok = tid >> 6, e = tid & 63;
      float acc[32];
      float bb = b2s[e];
#pragma unroll
      for (int t = 0; t < 32; t++) acc[t] = bb;
      for (int ic = 0; ic < 32; ic++) {
        float hv[36];
#pragma unroll
        for (int q = 0; q < 9; q++) ld4(&h1p[tok][ic][4 * q], &hv[4 * q]);
#pragma unroll
        for (int kk = 0; kk < 3; kk++) {
          float w = w2t[ic * 3 + kk][e];
#pragma unroll
          for (int t = 0; t < 32; t++) acc[t] += hv[t + kk] * w;
        }
      }
      float sum = 0.f;
#pragma unroll
      for (int t = 0; t < 32; t++) sum += fmaxf(acc[t], 0.f);
      int ti = base + tok;
      if (ti < cnt) {
        int n = idxbuf[g * 32768 + ti];
        hout[n * 64 + e] += sum * (1.f / 32.f);
      }
    }
  }
}

// Tiled GEMM: C[M][N] = A[M][K] @ W[N][K]^T + bias, optional relu.
// Block computes 64x64 tile; 4x4 register tile per thread.
__global__ __launch_bounds__(256, 4) void gemm_bias_kernel(
    const float* __restrict__ A, const float* __restrict__ W,
    const float* __restrict__ bias, float* __restrict__ C,
    int K, int N, int relu) {
  __shared__ __align__(16) float aT[64][68];
  __shared__ __align__(16) float bT[64][68];
  int n0 = blockIdx.x * 64;
  int c0 = blockIdx.y * 64;
  int tid = threadIdx.x;
  int tm = (tid & 15) * 4, tn = (tid >> 4) * 4;
  float acc[4][4] = {};
  for (int kc = 0; kc < K; kc += 64) {
    for (int i = tid; i < 4096; i += 256) {
      int m = i >> 6, k = i & 63;
      aT[k][m] = A[(n0 + m) * K + kc + k];
      bT[k][m] = W[(c0 + m) * K + kc + k];
    }
    __syncthreads();
#pragma unroll 8
    for (int k = 0; k < 64; k++) {
      float4 a = *reinterpret_cast<const float4*>(&aT[k][tm]);
      float4 b = *reinterpret_cast<const float4*>(&bT[k][tn]);
      acc[0][0] += a.x * b.x; acc[0][1] += a.x * b.y; acc[0][2] += a.x * b.z; acc[0][3] += a.x * b.w;
      acc[1][0] += a.y * b.x; acc[1][1] += a.y * b.y; acc[1][2] += a.y * b.z; acc[1][3] += a.y * b.w;
      acc[2][0] += a.z * b.x; acc[2][1] += a.z * b.y; acc[2][2] += a.z * b.z; acc[2][3] += a.z * b.w;
      acc[3][0] += a.w * b.x; acc[3][1] += a.w * b.y; acc[3][2] += a.w * b.z; acc[3][3] += a.w * b.w;
    }
    __syncthreads();
  }
#pragma unroll
  for (int i = 0; i < 4; i++) {
#pragma unroll
    for (int j = 0; j < 4; j++) {
      float v = acc[i][j] + bias[c0 + tn + j];
      if (relu) v = fmaxf(v, 0.f);
      C[(n0 + tm + i) * N + c0 + tn + j] = v;
    }
  }
}

// Attention over active keys only (mask is suffix: key s active iff s < len[b]).
// One block per (b, head); 128 threads; 2 queries per thread.
__global__ __launch_bounds__(128, 2) void attn_kernel(
    const float* __restrict__ qkv, const int* __restrict__ lens,
    float* __restrict__ o) {
  __shared__ __align__(16) float ks[256][16];
  __shared__ __align__(16) float vs[256][16];
  int bh = blockIdx.x;
  int b_ = bh >> 2, hd = bh & 3;
  int tid = threadIdx.x;
  int len = lens[b_];
  const float* base = qkv + b_ * 256 * 192;
  for (int i = tid; i < len * 16; i += 128) {
    int s = i >> 4, d = i & 15;
    ks[s][d] = base[s * 192 + 64 + hd * 16 + d];
    vs[s][d] = base[s * 192 + 128 + hd * 16 + d];
  }
  __syncthreads();
  float qv0[16], qv1[16];
  const float* q0 = base + tid * 192 + hd * 16;
  const float* q1 = base + (tid + 128) * 192 + hd * 16;
#pragma unroll
  for (int d = 0; d < 16; d++) { qv0[d] = q0[d] * 0.25f; qv1[d] = q1[d] * 0.25f; }
  float m0 = -1e30f, l0 = 0.f, m1 = -1e30f, l1 = 0.f;
  float a0[16], a1[16];
#pragma unroll
  for (int d = 0; d < 16; d++) { a0[d] = 0.f; a1[d] = 0.f; }
  for (int kk = 0; kk < len; kk++) {
    float kv[16], vv[16];
#pragma unroll
    for (int q = 0; q < 4; q++) { ld4(&ks[kk][4 * q], &kv[4 * q]); ld4(&vs[kk][4 * q], &vv[4 * q]); }
    float s0 = 0.f, s1 = 0.f;
#pragma unroll
    for (int d = 0; d < 16; d++) { s0 += qv0[d] * kv[d]; s1 += qv1[d] * kv[d]; }
    {
      float mn = fmaxf(m0, s0);
      float al = __expf(m0 - mn), pp = __expf(s0 - mn);
      l0 = l0 * al + pp;
#pragma unroll
      for (int d = 0; d < 16; d++) a0[d] = a0[d] * al + pp * vv[d];
      m0 = mn;
    }
    {
      float mn = fmaxf(m1, s1);
      float al = __expf(m1 - mn), pp = __expf(s1 - mn);
      l1 = l1 * al + pp;
#pragma unroll
      for (int d = 0; d < 16; d++) a1[d] = a1[d] * al + pp * vv[d];
      m1 = mn;
    }
  }
  float i0 = 1.f / l0, i1 = 1.f / l1;
  float* o0 = o + (b_ * 256 + tid) * 64 + hd * 16;
  float* o1 = o + (b_ * 256 + tid + 128) * 64 + hd * 16;
#pragma unroll
  for (int d = 0; d < 16; d++) { o0[d] = a0[d] * i0; o1[d] = a1[d] * i1; }
}

// h = LayerNorm(h + delta) — 4 rows/block, one wave per row.
__global__ __launch_bounds__(256) void resid_ln_kernel(
    float* __restrict__ h, const float* __restrict__ delta,
    const float* __restrict__ gg, const float* __restrict__ bb) {
  int wv = threadIdx.x >> 6, e = threadIdx.x & 63;
  int n = blockIdx.x * 4 + wv;
  float r = h[n * 64 + e] + delta[n * 64 + e];
  float sum = r;
#pragma unroll
  for (int off = 32; off; off >>= 1) sum += __shfl_xor(sum, off);
  float mean = sum * (1.f / 64.f);
  float dd = r - mean;
  float vsum = dd * dd;
#pragma unroll
  for (int off = 32; off; off >>= 1) vsum += __shfl_xor(vsum, off);
  float var = vsum * (1.f / 64.f);
  h[n * 64 + e] = dd * rsqrtf(var + 1e-5f) * gg[e] + bb[e];
}

// Masked mean pool using per-b active length (mask is suffix).
__global__ __launch_bounds__(256) void pool_kernel(
    const float* __restrict__ h, const int* __restrict__ lens,
    float* __restrict__ pooled) {
  __shared__ float ps[4][64];
  int b = blockIdx.x;
  int e = threadIdx.x & 63, sp = threadIdx.x >> 6;
  int len = lens[b];
  float sum = 0.f;
  int send = min(sp * 64 + 64, len);
  for (int s = sp * 64; s < send; s++) sum += h[(b * 256 + s) * 64 + e];
  ps[sp][e] = sum;
  __syncthreads();
  if (sp == 0) {
    float tot = ps[0][e] + ps[1][e] + ps[2][e] + ps[3][e];
    pooled[b * 64 + e] = tot / ((float)len + 1e-8f);
  }
}

// Fused heads: cls(3), mus(6), sigmas(6), d(1) -> 16 outputs per b.
__global__ __launch_bounds__(64) void heads_kernel(
    const float* __restrict__ pooled,
    const float* __restrict__ cls_w1, const float* __restrict__ cls_b1,
    const float* __restrict__ cls_w2, const float* __restrict__ cls_b2,
    const float* __restrict__ mu_w1, const float* __restrict__ mu_b1,
    const float* __restrict__ mu_w2, const float* __restrict__ mu_b2,
    const float* __restrict__ ls_w1, const float* __restrict__ ls_b1,
    const float* __restrict__ ls_w2, const float* __restrict__ ls_b2,
    const float* __restrict__ d_w1, const float* __restrict__ d_b1,
    const float* __restrict__ d_w2, const float* __restrict__ d_b2,
    float* __restrict__ out) {
  int b = blockIdx.x, e = threadIdx.x;
  __shared__ float p[64];
  __shared__ float t1[64];
  p[e] = pooled[b * 64 + e];
  __syncthreads();
  {
    float a = cls_b1[e];
    for (int j = 0; j < 64; j++) a += p[j] * cls_w1[e * 64 + j];
    t1[e] = fmaxf(a, 0.f);
  }
  __syncthreads();
  if (e < 3) {
    float a2 = cls_b2[e];
    for (int j = 0; j < 64; j++) a2 += t1[j] * cls_w2[e * 64 + j];
    out[b * 16 + e] = a2;
  }
  for (int z = 0; z < 3; z++) {
    __syncthreads();
    {
      float a = mu_b1[z * 64 + e];
      for (int j = 0; j < 64; j++) a += p[j] * mu_w1[(z * 64 + e) * 64 + j];
      t1[e] = fmaxf(a, 0.f);
    }
    __syncthreads();
    if (e < 2) {
      float a2 = mu_b2[z * 2 + e];
      for (int j = 0; j < 64; j++) a2 += t1[j] * mu_w2[(z * 2 + e) * 64 + j];
      out[b * 16 + 3 + z * 2 + e] = a2;
    }
    __syncthreads();
    {
      float a = ls_b1[z * 64 + e];
      for (int j = 0; j < 64; j++) a += p[j] * ls_w1[(z * 64 + e) * 64 + j];
      t1[e] = fmaxf(a, 0.f);
    }
    __syncthreads();
    if (e < 2) {
      float a2 = ls_b2[z * 2 + e];
      for (int j = 0; j < 64; j++) a2 += t1[j] * ls_w2[(z * 2 + e) * 64 + j];
      out[b * 16 + 9 + z * 2 + e] = __expf(a2);
    }
  }
  __syncthreads();
  {
    float a = d_b1[e];
    for (int j = 0; j < 64; j++) a += p[j] * d_w1[e * 64 + j];
    t1[e] = fmaxf(a, 0.f);
  }
  __syncthreads();
  if (e == 0) {
    float a2 = d_b2[0];
    for (int j = 0; j < 64; j++) a2 += t1[j] * d_w2[j];
    out[b * 16 + 15] = 1.f / (1.f + __expf(-a2));
  }
}

extern "C" void kernel_launch(void* const* d_in, const int* in_sizes, int n_in,
                              void* d_out, int out_size, void* d_ws, size_t ws_size,
                              hipStream_t stream) {
  const float* wav       = (const float*)d_in[0];
  const int*   sid       = (const int*)d_in[1];
  const void*  mask      = d_in[2];
  const float* conv1_w   = (const float*)d_in[3];
  const float* conv1_b   = (const float*)d_in[4];
  const float* conv2_w   = (const float*)d_in[5];
  const float* conv2_b   = (const float*)d_in[6];
  const float* shank_emb = (const float*)d_in[7];
  const float* in_proj_w = (const float*)d_in[8];
  const float* in_proj_b = (const float*)d_in[9];
  const float* out_proj_w= (const float*)d_in[10];
  const float* out_proj_b= (const float*)d_in[11];
  const float* ln1_g     = (const float*)d_in[12];
  const float* ln1_b     = (const float*)d_in[13];
  const float* ff1_w     = (const float*)d_in[14];
  const float* ff1_b     = (const float*)d_in[15];
  const float* ff2_w     = (const float*)d_in[16];
  const float* ff2_b     = (const float*)d_in[17];
  const float* ln2_g     = (const float*)d_in[18];
  const float* ln2_b     = (const float*)d_in[19];
  const float* cls_w1    = (const float*)d_in[20];
  const float* cls_b1    = (const float*)d_in[21];
  const float* cls_w2    = (const float*)d_in[22];
  const float* cls_b2    = (const float*)d_in[23];
  const float* mu_w1     = (const float*)d_in[24];
  const float* mu_b1     = (const float*)d_in[25];
  const float* mu_w2     = (const float*)d_in[26];
  const float* mu_b2     = (const float*)d_in[27];
  const float* ls_w1     = (const float*)d_in[28];
  const float* ls_b1     = (const float*)d_in[29];
  const float* ls_w2     = (const float*)d_in[30];
  const float* ls_b2     = (const float*)d_in[31];
  const float* d_w1      = (const float*)d_in[32];
  const float* d_b1      = (const float*)d_in[33];
  const float* d_w2      = (const float*)d_in[34];
  const float* d_b2      = (const float*)d_in[35];
  float* out = (float*)d_out;

  float* ws = (float*)d_ws;
  float* h      = ws;                    // [32768,64]
  float* qkv    = ws + 2097152;          // [32768,192]
  float* obuf   = ws + 8388608;          // [32768,64] attn out
  float* aux    = ws + 10485760;         // [32768,64] proj / ff2 out
  float* ff     = ws + 2097152;          // [32768,256] aliases qkv+obuf (dead by ff1)
  float* pooled = ws + 12582912;         // [128,64]
  int*   ip     = (int*)(ws + 12591104);
  int*   flag   = ip;
  int*   counts = ip + 8;
  int*   lens   = ip + 16;               // [128]
  int*   idxbuf = ip + 144;              // [8][32768]

  detect_mask_kernel<<<1, 256, 0, stream>>>((const unsigned int*)mask, flag, counts, lens);
  bin_kernel<<<128, 256, 0, stream>>>(sid, mask, flag, counts, lens, idxbuf);
  init_emb_kernel<<<8192, 256, 0, stream>>>(sid, shank_emb, h);
  conv_kernel<<<CONV_BPG * 8, 256, 0, stream>>>(idxbuf, counts, wav, conv1_w, conv1_b,
                                                conv2_w, conv2_b, h);
  for (int l = 0; l < 2; l++) {
    gemm_bias_kernel<<<dim3(512, 3), 256, 0, stream>>>(
        h, in_proj_w + l * 12288, in_proj_b + l * 192, qkv, 64, 192, 0);
    attn_kernel<<<512, 128, 0, stream>>>(qkv, lens, obuf);
    gemm_bias_kernel<<<dim3(512, 1), 256, 0, stream>>>(
        obuf, out_proj_w + l * 4096, out_proj_b + l * 64, aux, 64, 64, 0);
    resid_ln_kernel<<<8192, 256, 0, stream>>>(h, aux, ln1_g + l * 64, ln1_b + l * 64);
    gemm_bias_kernel<<<dim3(512, 4), 256, 0, stream>>>(
        h, ff1_w + l * 16384, ff1_b + l * 256, ff, 64, 256, 1);
    gemm_bias_kernel<<<dim3(512, 1), 256, 0, stream>>>(
        ff, ff2_w + l * 16384, ff2_b + l * 64, aux, 256, 64, 0);
    resid_ln_kernel<<<8192, 256, 0, stream>>>(h, aux, ln2_g + l * 64, ln2_b + l * 64);
  }
  pool_kernel<<<128, 256, 0, stream>>>(h, lens, pooled);
  heads_kernel<<<128, 64, 0, stream>>>(pooled, cls_w1, cls_b1, cls_w2, cls_b2,
                                       mu_w1, mu_b1, mu_w2, mu_b2,
                                       ls_w1, ls_b1, ls_w2, ls_b2,
                                       d_w1, d_b1, d_w2, d_b2, out);
}

// Round 3
// 593.839 us; speedup vs baseline: 2.8816x; 1.5333x over previous
//
#include <hip/hip_runtime.h>
#include <math.h>

// B=128, S=256, G=8, CMAX=6, T=32, E=64, NH=4, dh=16, L=2, DFF=256, Z=3

typedef short bf16x8 __attribute__((ext_vector_type(8)));
typedef float f32x4 __attribute__((ext_vector_type(4)));

__device__ __forceinline__ unsigned short f2bf(float f) {
  unsigned u = __float_as_uint(f);
  u += 0x7fffu + ((u >> 16) & 1u);   // RNE
  return (unsigned short)(u >> 16);
}

__device__ __forceinline__ bf16x8 ldfrag(const unsigned short* p) {
  return *reinterpret_cast<const bf16x8*>(p);
}

__device__ __forceinline__ void ld4(const float* p, float* dst) {
  float4 t = *reinterpret_cast<const float4*>(p);
  dst[0] = t.x; dst[1] = t.y; dst[2] = t.z; dst[3] = t.w;
}

__device__ __forceinline__ bool is_masked(const void* mask_, int flag, int idx) {
  return flag ? (((const unsigned char*)mask_)[idx] != 0)
              : (((const int*)mask_)[idx] != 0);
}

// Detect mask dtype (int32 vs byte-packed bool); zero counters.
__global__ void detect_mask_kernel(const unsigned int* __restrict__ mw,
                                   int* __restrict__ flag, int* __restrict__ counts,
                                   int* __restrict__ lens) {
  __shared__ int sh;
  if (threadIdx.x == 0) sh = 0;
  __syncthreads();
  int bad = 0;
  for (int i = threadIdx.x; i < 8192; i += 256)
    if (mw[i] > 1u) bad = 1;
  if (bad) atomicOr(&sh, 1);
  if (threadIdx.x < 8) counts[threadIdx.x] = 0;
  if (threadIdx.x < 128) lens[threadIdx.x] = 0;
  __syncthreads();
  if (threadIdx.x == 0) *flag = sh;
}

// Bin active tokens by shank id; count active tokens per batch (mask is a suffix).
__global__ void bin_kernel(const int* __restrict__ sid, const void* __restrict__ mask_,
                           const int* __restrict__ flagp, int* __restrict__ counts,
                           int* __restrict__ lens, int* __restrict__ idxbuf) {
  int n = blockIdx.x * 256 + threadIdx.x;
  int flag = *flagp;
  if (!is_masked(mask_, flag, n)) {
    int g = sid[n];
    int pos = atomicAdd(&counts[g], 1);
    idxbuf[g * 32768 + pos] = n;
    atomicAdd(&lens[n >> 8], 1);
  }
}

// Base embedding: shank_emb[sid] + positional encoding.
__global__ __launch_bounds__(256) void init_emb_kernel(
    const int* __restrict__ sid, const float* __restrict__ shank_emb,
    float* __restrict__ hout) {
  int i = blockIdx.x * 256 + threadIdx.x;
  int n = i >> 6, e = i & 63, s = n & 255;
  int g = sid[n];
  float div = __expf(-(float)(e & ~1) * (9.21034037f / 64.f));
  float angle = (float)s * div;
  float pe = (e & 1) ? cosf(angle) : sinf(angle);
  hout[i] = shank_emb[g * 64 + e] + pe;
}

// Conv encoder via bf16 MFMA. t-major LDS layouts make each conv tap a
// K-contiguous GEMM term (no im2col duplication).
// conv1: out[t][oc] = sum_{k=0..4} sum_{ic} xT[t+k][ic] * w1f[k][oc][ic]
//        taps 0-3 packed into one K=32 MFMA (quad q holds k-slots of tap q).
// conv2: out[t][e]  = sum_{k=0..2} sum_{ic=0..31} h1T[t+k][ic] * w2f[k][e][ic]
#define CONV_BPG 64
__global__ __launch_bounds__(256) void conv_mfma_kernel(
    const int* __restrict__ idxbuf, const int* __restrict__ counts,
    const float* __restrict__ wav,
    const float* __restrict__ w1_, const float* __restrict__ b1_,
    const float* __restrict__ w2_, const float* __restrict__ b2_,
    float* __restrict__ hout) {
  __shared__ __align__(16) unsigned short w1f[5][32][8];    // [tap][oc][ic pad8]
  __shared__ __align__(16) unsigned short w2f[3][64][40];   // [tap][e][ic pad40]
  __shared__ float b1s[32];
  __shared__ float b2s[64];
  __shared__ __align__(16) unsigned short xT[8][36][8];     // [tok][tpad][ic pad8]
  __shared__ __align__(16) unsigned short h1T[8][34][40];   // [tok][tpad][oc pad40]
  int g = blockIdx.x & 7, bib = blockIdx.x >> 3;
  int tid = threadIdx.x;
  int wv = tid >> 6, lane = tid & 63, quad = lane >> 4, l15 = lane & 15;
  // stage weights as bf16 (one-time)
  for (int i = tid; i < 1280; i += 256) {
    int k = i >> 8, rest = i & 255, oc = rest >> 3, ic = rest & 7;
    w1f[k][oc][ic] = (ic < 6) ? f2bf(w1_[g * 960 + oc * 30 + ic * 5 + k]) : 0;
  }
  for (int i = tid; i < 7680; i += 256) {
    int k = i / 2560, rest = i % 2560, e = rest / 40, ic = rest % 40;
    w2f[k][e][ic] = (ic < 32) ? f2bf(w2_[g * 6144 + e * 96 + ic * 3 + k]) : 0;
  }
  if (tid < 32) b1s[tid] = b1_[g * 32 + tid];
  if (tid < 64) b2s[tid] = b2_[g * 64 + tid];
  // zero h1T pad rows 0 and 33 (never written by conv1)
  for (int i = tid; i < 640; i += 256) {
    int tok = i / 80, rest = i % 80;
    h1T[tok][(rest >= 40) ? 33 : 0][rest % 40] = 0;
  }
  __syncthreads();
  // token-invariant B fragments -> registers
  bf16x8 zf = {0, 0, 0, 0, 0, 0, 0, 0};
  bf16x8 bf1[2], bf1k4[2], bf2[3][4];
#pragma unroll
  for (int nt = 0; nt < 2; nt++) {
    bf1[nt] = ldfrag(&w1f[quad][nt * 16 + l15][0]);
    bf1k4[nt] = (quad == 0) ? ldfrag(&w1f[4][nt * 16 + l15][0]) : zf;
  }
#pragma unroll
  for (int k = 0; k < 3; k++)
#pragma unroll
    for (int nt = 0; nt < 4; nt++)
      bf2[k][nt] = ldfrag(&w2f[k][nt * 16 + l15][quad * 8]);
  float b1v0 = b1s[l15], b1v1 = b1s[16 + l15];
  int cnt = counts[g];
  for (int base = bib * 8; base < cnt; base += CONV_BPG * 8) {
    __syncthreads();
    // stage 8 tokens' waveforms, t-major bf16, zero pad 2 each side
    for (int i = tid; i < 2304; i += 256) {
      int tok = i / 288, rest = i % 288, row = rest >> 3, ic = rest & 7;
      unsigned short v = 0;
      int ti = base + tok;
      if (ti < cnt && ic < 6 && row >= 2 && row < 34)
        v = f2bf(wav[idxbuf[g * 32768 + ti] * 192 + ic * 32 + (row - 2)]);
      xT[tok][row][ic] = v;
    }
    __syncthreads();
    // conv1 (each wave: 2 token slots)
#pragma unroll
    for (int ts = 0; ts < 2; ts++) {
      int tk = wv * 2 + ts;
      f32x4 c1[2][2];
#pragma unroll
      for (int mt = 0; mt < 2; mt++) {
        c1[mt][0] = (f32x4){b1v0, b1v0, b1v0, b1v0};
        c1[mt][1] = (f32x4){b1v1, b1v1, b1v1, b1v1};
      }
#pragma unroll
      for (int mt = 0; mt < 2; mt++) {
        bf16x8 afm = ldfrag(&xT[tk][mt * 16 + l15 + quad][0]);
        bf16x8 af4 = (quad == 0) ? ldfrag(&xT[tk][mt * 16 + l15 + 4][0]) : zf;
#pragma unroll
        for (int nt = 0; nt < 2; nt++) {
          c1[mt][nt] = __builtin_amdgcn_mfma_f32_16x16x32_bf16(afm, bf1[nt], c1[mt][nt], 0, 0, 0);
          c1[mt][nt] = __builtin_amdgcn_mfma_f32_16x16x32_bf16(af4, bf1k4[nt], c1[mt][nt], 0, 0, 0);
        }
      }
#pragma unroll
      for (int mt = 0; mt < 2; mt++)
#pragma unroll
        for (int nt = 0; nt < 2; nt++)
#pragma unroll
          for (int r = 0; r < 4; r++) {
            int t = mt * 16 + quad * 4 + r;
            h1T[tk][t + 1][nt * 16 + l15] = f2bf(fmaxf(c1[mt][nt][r], 0.f));
          }
    }
    __syncthreads();
    // conv2 + relu + mean + scatter-add
#pragma unroll
    for (int ts = 0; ts < 2; ts++) {
      int tk = wv * 2 + ts;
      f32x4 c2[2][4];
#pragma unroll
      for (int mt = 0; mt < 2; mt++)
#pragma unroll
        for (int nt = 0; nt < 4; nt++) {
          float bv = b2s[nt * 16 + l15];
          c2[mt][nt] = (f32x4){bv, bv, bv, bv};
        }
#pragma unroll
      for (int k = 0; k < 3; k++)
#pragma unroll
        for (int mt = 0; mt < 2; mt++) {
          bf16x8 af = ldfrag(&h1T[tk][mt * 16 + l15 + k][quad * 8]);
#pragma unroll
          for (int nt = 0; nt < 4; nt++)
            c2[mt][nt] = __builtin_amdgcn_mfma_f32_16x16x32_bf16(af, bf2[k][nt], c2[mt][nt], 0, 0, 0);
        }
      int ti = base + tk;
      float sums[4];
#pragma unroll
      for (int nt = 0; nt < 4; nt++) {
        float s = 0.f;
#pragma unroll
        for (int mt = 0; mt < 2; mt++)
#pragma unroll
          for (int r = 0; r < 4; r++) s += fmaxf(c2[mt][nt][r], 0.f);
        s += __shfl_xor(s, 16);
        s += __shfl_xor(s, 32);
        sums[nt] = s;
      }
      if (ti < cnt && quad == 0) {
        int n = idxbuf[g * 32768 + ti];
#pragma unroll
        for (int nt = 0; nt < 4; nt++)
          hout[n * 64 + nt * 16 + l15] += sums[nt] * (1.f / 32.f);
      }
    }
  }
}

// bf16-MFMA GEMM: out = A[M][K] @ W[N][K]^T + bias.
// mode 0: store to C. mode 1: relu, store to C. mode 2: H = LayerNorm(H + out).
__global__ __launch_bounds__(256) void mfma_gemm_kernel(
    const float* __restrict__ A, const float* __restrict__ W,
    const float* __restrict__ bias, float* __restrict__ C,
    float* __restrict__ H, const float* __restrict__ lng,
    const float* __restrict__ lnb, int K, int N, int mode) {
  __shared__ __align__(16) unsigned short As[64][72];
  __shared__ __align__(16) unsigned short Bs[64][72];
  int m0 = blockIdx.x * 64, c0 = blockIdx.y * 64;
  int tid = threadIdx.x;
  int wv = tid >> 6, lane = tid & 63, quad = lane >> 4, l15 = lane & 15;
  f32x4 acc[4];
#pragma unroll
  for (int nt = 0; nt < 4; nt++) {
    float b = bias[c0 + nt * 16 + l15];
    acc[nt] = (f32x4){b, b, b, b};
  }
  for (int kc = 0; kc < K; kc += 64) {
    __syncthreads();
    for (int i = tid; i < 1024; i += 256) {
      int r = i >> 4, c4 = (i & 15) << 2;
      float4 av = *(const float4*)&A[(size_t)(m0 + r) * K + kc + c4];
      short4 t;
      t.x = (short)f2bf(av.x); t.y = (short)f2bf(av.y);
      t.z = (short)f2bf(av.z); t.w = (short)f2bf(av.w);
      *(short4*)&As[r][c4] = t;
      float4 wv4 = *(const float4*)&W[(size_t)(c0 + r) * K + kc + c4];
      short4 u;
      u.x = (short)f2bf(wv4.x); u.y = (short)f2bf(wv4.y);
      u.z = (short)f2bf(wv4.z); u.w = (short)f2bf(wv4.w);
      *(short4*)&Bs[r][c4] = u;
    }
    __syncthreads();
#pragma unroll
    for (int ks = 0; ks < 64; ks += 32) {
      bf16x8 af = ldfrag(&As[wv * 16 + l15][ks + quad * 8]);
#pragma unroll
      for (int nt = 0; nt < 4; nt++) {
        bf16x8 bfr = ldfrag(&Bs[nt * 16 + l15][ks + quad * 8]);
        acc[nt] = __builtin_amdgcn_mfma_f32_16x16x32_bf16(af, bfr, acc[nt], 0, 0, 0);
      }
    }
  }
  int mrow = m0 + wv * 16 + quad * 4;
  if (mode <= 1) {
#pragma unroll
    for (int nt = 0; nt < 4; nt++)
#pragma unroll
      for (int r = 0; r < 4; r++) {
        float v = acc[nt][r];
        if (mode == 1) v = fmaxf(v, 0.f);
        C[(size_t)(mrow + r) * N + c0 + nt * 16 + l15] = v;
      }
  } else {
#pragma unroll
    for (int r = 0; r < 4; r++) {
      float rv[4];
      float s = 0.f;
#pragma unroll
      for (int nt = 0; nt < 4; nt++) {
        float v = acc[nt][r] + H[(size_t)(mrow + r) * 64 + nt * 16 + l15];
        rv[nt] = v; s += v;
      }
      s += __shfl_xor(s, 1); s += __shfl_xor(s, 2);
      s += __shfl_xor(s, 4); s += __shfl_xor(s, 8);
      float mean = s * (1.f / 64.f);
      float vsum = 0.f;
#pragma unroll
      for (int nt = 0; nt < 4; nt++) { rv[nt] -= mean; vsum += rv[nt] * rv[nt]; }
      vsum += __shfl_xor(vsum, 1); vsum += __shfl_xor(vsum, 2);
      vsum += __shfl_xor(vsum, 4); vsum += __shfl_xor(vsum, 8);
      float inv = rsqrtf(vsum * (1.f / 64.f) + 1e-5f);
#pragma unroll
      for (int nt = 0; nt < 4; nt++) {
        int col = nt * 16 + l15;
        H[(size_t)(mrow + r) * 64 + col] = rv[nt] * inv * lng[col] + lnb[col];
      }
    }
  }
}

// Attention: block = (b, head, q-quarter); thread = (query, key-slice of 4).
// Online softmax per slice, then shfl_xor merge across slices.
__global__ __launch_bounds__(256) void attn_kernel(
    const float* __restrict__ qkv, const int* __restrict__ lens,
    float* __restrict__ o) {
  __shared__ __align__(16) float ks[256][16];
  __shared__ __align__(16) float vs[256][16];
  int bh = blockIdx.x >> 2, qblk = blockIdx.x & 3;
  int b_ = bh >> 2, hd = bh & 3;
  int tid = threadIdx.x;
  int len = lens[b_];
  const float* base = qkv + b_ * 256 * 192;
  for (int i = tid; i < len * 4; i += 256) {
    int s = i >> 2, c = (i & 3) << 2;
    *(float4*)&ks[s][c] = *(const float4*)&base[s * 192 + 64 + hd * 16 + c];
    *(float4*)&vs[s][c] = *(const float4*)&base[s * 192 + 128 + hd * 16 + c];
  }
  __syncthreads();
  int q = qblk * 64 + (tid >> 2), slice = tid & 3;
  float qv[16];
  const float* qp = base + q * 192 + hd * 16;
#pragma unroll
  for (int d = 0; d < 16; d++) qv[d] = qp[d] * 0.25f;
  float m = -1e30f, l = 0.f, acc[16] = {};
  for (int kk = slice; kk < len; kk += 4) {
    float kv[16], vv[16];
#pragma unroll
    for (int c = 0; c < 4; c++) { ld4(&ks[kk][c * 4], &kv[c * 4]); ld4(&vs[kk][c * 4], &vv[c * 4]); }
    float sc = 0.f;
#pragma unroll
    for (int d = 0; d < 16; d++) sc += qv[d] * kv[d];
    float mn = fmaxf(m, sc);
    float al = __expf(m - mn), pp = __expf(sc - mn);
    l = l * al + pp;
#pragma unroll
    for (int d = 0; d < 16; d++) acc[d] = acc[d] * al + pp * vv[d];
    m = mn;
  }
#pragma unroll
  for (int off = 1; off <= 2; off <<= 1) {
    float mo = __shfl_xor(m, off);
    float lo = __shfl_xor(l, off);
    float mn = fmaxf(m, mo);
    float sa = __expf(m - mn), sb = __expf(mo - mn);
    l = l * sa + lo * sb;
#pragma unroll
    for (int d = 0; d < 16; d++) {
      float ao = __shfl_xor(acc[d], off);
      acc[d] = acc[d] * sa + ao * sb;
    }
    m = mn;
  }
  float inv = 1.f / l;
  float* op = o + (b_ * 256 + q) * 64 + hd * 16 + slice * 4;
#pragma unroll
  for (int j = 0; j < 4; j++) op[j] = acc[slice * 4 + j] * inv;
}

// Masked mean pool using per-b active length.
__global__ __launch_bounds__(256) void pool_kernel(
    const float* __restrict__ h, const int* __restrict__ lens,
    float* __restrict__ pooled) {
  __shared__ float ps[4][64];
  int b = blockIdx.x;
  int e = threadIdx.x & 63, sp = threadIdx.x >> 6;
  int len = lens[b];
  float sum = 0.f;
  int send = min(sp * 64 + 64, len);
  for (int s = sp * 64; s < send; s++) sum += h[(b * 256 + s) * 64 + e];
  ps[sp][e] = sum;
  __syncthreads();
  if (sp == 0) {
    float tot = ps[0][e] + ps[1][e] + ps[2][e] + ps[3][e];
    pooled[b * 64 + e] = tot / ((float)len + 1e-8f);
  }
}

// Fused heads: cls(3), mus(6), sigmas(6), d(1) -> 16 outputs per b.
__global__ __launch_bounds__(64) void heads_kernel(
    const float* __restrict__ pooled,
    const float* __restrict__ cls_w1, const float* __restrict__ cls_b1,
    const float* __restrict__ cls_w2, const float* __restrict__ cls_b2,
    const float* __restrict__ mu_w1, const float* __restrict__ mu_b1,
    const float* __restrict__ mu_w2, const float* __restrict__ mu_b2,
    const float* __restrict__ ls_w1, const float* __restrict__ ls_b1,
    const float* __restrict__ ls_w2, const float* __restrict__ ls_b2,
    const float* __restrict__ d_w1, const float* __restrict__ d_b1,
    const float* __restrict__ d_w2, const float* __restrict__ d_b2,
    float* __restrict__ out) {
  int b = blockIdx.x, e = threadIdx.x;
  __shared__ float p[64];
  __shared__ float t1[64];
  p[e] = pooled[b * 64 + e];
  __syncthreads();
  {
    float a = cls_b1[e];
    for (int j = 0; j < 64; j++) a += p[j] * cls_w1[e * 64 + j];
    t1[e] = fmaxf(a, 0.f);
  }
  __syncthreads();
  if (e < 3) {
    float a2 = cls_b2[e];
    for (int j = 0; j < 64; j++) a2 += t1[j] * cls_w2[e * 64 + j];
    out[b * 16 + e] = a2;
  }
  for (int z = 0; z < 3; z++) {
    __syncthreads();
    {
      float a = mu_b1[z * 64 + e];
      for (int j = 0; j < 64; j++) a += p[j] * mu_w1[(z * 64 + e) * 64 + j];
      t1[e] = fmaxf(a, 0.f);
    }
    __syncthreads();
    if (e < 2) {
      float a2 = mu_b2[z * 2 + e];
      for (int j = 0; j < 64; j++) a2 += t1[j] * mu_w2[(z * 2 + e) * 64 + j];
      out[b * 16 + 3 + z * 2 + e] = a2;
    }
    __syncthreads();
    {
      float a = ls_b1[z * 64 + e];
      for (int j = 0; j < 64; j++) a += p[j] * ls_w1[(z * 64 + e) * 64 + j];
      t1[e] = fmaxf(a, 0.f);
    }
    __syncthreads();
    if (e < 2) {
      float a2 = ls_b2[z * 2 + e];
      for (int j = 0; j < 64; j++) a2 += t1[j] * ls_w2[(z * 2 + e) * 64 + j];
      out[b * 16 + 9 + z * 2 + e] = __expf(a2);
    }
  }
  __syncthreads();
  {
    float a = d_b1[e];
    for (int j = 0; j < 64; j++) a += p[j] * d_w1[e * 64 + j];
    t1[e] = fmaxf(a, 0.f);
  }
  __syncthreads();
  if (e == 0) {
    float a2 = d_b2[0];
    for (int j = 0; j < 64; j++) a2 += t1[j] * d_w2[j];
    out[b * 16 + 15] = 1.f / (1.f + __expf(-a2));
  }
}

extern "C" void kernel_launch(void* const* d_in, const int* in_sizes, int n_in,
                              void* d_out, int out_size, void* d_ws, size_t ws_size,
                              hipStream_t stream) {
  const float* wav       = (const float*)d_in[0];
  const int*   sid       = (const int*)d_in[1];
  const void*  mask      = d_in[2];
  const float* conv1_w   = (const float*)d_in[3];
  const float* conv1_b   = (const float*)d_in[4];
  const float* conv2_w   = (const float*)d_in[5];
  const float* conv2_b   = (const float*)d_in[6];
  const float* shank_emb = (const float*)d_in[7];
  const float* in_proj_w = (const float*)d_in[8];
  const float* in_proj_b = (const float*)d_in[9];
  const float* out_proj_w= (const float*)d_in[10];
  const float* out_proj_b= (const float*)d_in[11];
  const float* ln1_g     = (const float*)d_in[12];
  const float* ln1_b     = (const float*)d_in[13];
  const float* ff1_w     = (const float*)d_in[14];
  const float* ff1_b     = (const float*)d_in[15];
  const float* ff2_w     = (const float*)d_in[16];
  const float* ff2_b     = (const float*)d_in[17];
  const float* ln2_g     = (const float*)d_in[18];
  const float* ln2_b     = (const float*)d_in[19];
  const float* cls_w1    = (const float*)d_in[20];
  const float* cls_b1    = (const float*)d_in[21];
  const float* cls_w2    = (const float*)d_in[22];
  const float* cls_b2    = (const float*)d_in[23];
  const float* mu_w1     = (const float*)d_in[24];
  const float* mu_b1     = (const float*)d_in[25];
  const float* mu_w2     = (const float*)d_in[26];
  const float* mu_b2     = (const float*)d_in[27];
  const float* ls_w1     = (const float*)d_in[28];
  const float* ls_b1     = (const float*)d_in[29];
  const float* ls_w2     = (const float*)d_in[30];
  const float* ls_b2     = (const float*)d_in[31];
  const float* d_w1      = (const float*)d_in[32];
  const float* d_b1      = (const float*)d_in[33];
  const float* d_w2      = (const float*)d_in[34];
  const float* d_b2      = (const float*)d_in[35];
  float* out = (float*)d_out;

  float* ws = (float*)d_ws;
  float* h      = ws;                    // [32768,64]
  float* qkv    = ws + 2097152;          // [32768,192]
  float* obuf   = ws + 8388608;          // [32768,64] attn out
  float* ff     = ws + 2097152;          // [32768,256] aliases qkv+obuf (dead by ff1)
  float* pooled = ws + 10485760;         // [128,64]
  int*   ip     = (int*)(ws + 10493952);
  int*   flag   = ip;
  int*   counts = ip + 8;
  int*   lens   = ip + 16;               // [128]
  int*   idxbuf = ip + 144;              // [8][32768]

  detect_mask_kernel<<<1, 256, 0, stream>>>((const unsigned int*)mask, flag, counts, lens);
  bin_kernel<<<128, 256, 0, stream>>>(sid, mask, flag, counts, lens, idxbuf);
  init_emb_kernel<<<8192, 256, 0, stream>>>(sid, shank_emb, h);
  conv_mfma_kernel<<<CONV_BPG * 8, 256, 0, stream>>>(idxbuf, counts, wav, conv1_w, conv1_b,
                                                     conv2_w, conv2_b, h);
  for (int l = 0; l < 2; l++) {
    mfma_gemm_kernel<<<dim3(512, 3), 256, 0, stream>>>(
        h, in_proj_w + l * 12288, in_proj_b + l * 192, qkv, h, ln1_g, ln1_b, 64, 192, 0);
    attn_kernel<<<2048, 256, 0, stream>>>(qkv, lens, obuf);
    mfma_gemm_kernel<<<dim3(512, 1), 256, 0, stream>>>(
        obuf, out_proj_w + l * 4096, out_proj_b + l * 64, obuf, h,
        ln1_g + l * 64, ln1_b + l * 64, 64, 64, 2);
    mfma_gemm_kernel<<<dim3(512, 4), 256, 0, stream>>>(
        h, ff1_w + l * 16384, ff1_b + l * 256, ff, h, ln2_g, ln2_b, 64, 256, 1);
    mfma_gemm_kernel<<<dim3(512, 1), 256, 0, stream>>>(
        ff, ff2_w + l * 16384, ff2_b + l * 64, ff, h,
        ln2_g + l * 64, ln2_b + l * 64, 256, 64, 2);
  }
  pool_kernel<<<128, 256, 0, stream>>>(h, lens, pooled);
  heads_kernel<<<128, 64, 0, stream>>>(pooled, cls_w1, cls_b1, cls_w2, cls_b2,
                                       mu_w1, mu_b1, mu_w2, mu_b2,
                                       ls_w1, ls_b1, ls_w2, ls_b2,
                                       d_w1, d_b1, d_w2, d_b2, out);
}

// Round 4
// 451.245 us; speedup vs baseline: 3.7921x; 1.3160x over previous
//
#include <hip/hip_runtime.h>
#include <math.h>

// B=128, S=256, G=8, CMAX=6, T=32, E=64, NH=4, dh=16, L=2, DFF=256, Z=3

typedef short bf16x8 __attribute__((ext_vector_type(8)));
typedef float f32x4 __attribute__((ext_vector_type(4)));

__device__ __forceinline__ unsigned short f2bf(float f) {
  unsigned u = __float_as_uint(f);
  u += 0x7fffu + ((u >> 16) & 1u);   // RNE
  return (unsigned short)(u >> 16);
}

__device__ __forceinline__ bf16x8 ldfrag(const unsigned short* p) {
  return *reinterpret_cast<const bf16x8*>(p);
}

__device__ __forceinline__ void ld4(const float* p, float* dst) {
  float4 t = *reinterpret_cast<const float4*>(p);
  dst[0] = t.x; dst[1] = t.y; dst[2] = t.z; dst[3] = t.w;
}

__device__ __forceinline__ bool is_masked(const void* mask_, int flag, int idx) {
  return flag ? (((const unsigned char*)mask_)[idx] != 0)
              : (((const int*)mask_)[idx] != 0);
}

// Detect mask dtype (int32 vs byte-packed bool); zero counters.
__global__ void detect_mask_kernel(const unsigned int* __restrict__ mw,
                                   int* __restrict__ flag, int* __restrict__ counts,
                                   int* __restrict__ lens) {
  __shared__ int sh;
  if (threadIdx.x == 0) sh = 0;
  __syncthreads();
  int bad = 0;
  for (int i = threadIdx.x; i < 8192; i += 256)
    if (mw[i] > 1u) bad = 1;
  if (bad) atomicOr(&sh, 1);
  if (threadIdx.x < 8) counts[threadIdx.x] = 0;
  if (threadIdx.x < 128) lens[threadIdx.x] = 0;
  __syncthreads();
  if (threadIdx.x == 0) *flag = sh;
}

// Bin active tokens by shank id. Hierarchical: LDS counters per block (8-way),
// one global atomicAdd per (block,g) to reserve chunks, then scatter.
// lens[b] = block's active count (block == batch row since S=256).
__global__ __launch_bounds__(256) void bin_kernel(
    const int* __restrict__ sid, const void* __restrict__ mask_,
    const int* __restrict__ flagp, int* __restrict__ counts,
    int* __restrict__ lens, int* __restrict__ idxbuf) {
  __shared__ int lcnt[8];
  __shared__ int lbase[8];
  int b = blockIdx.x, tid = threadIdx.x;
  int n = b * 256 + tid;
  int flag = *flagp;
  bool act = !is_masked(mask_, flag, n);
  int g = act ? sid[n] : 0;
  if (tid < 8) lcnt[tid] = 0;
  __syncthreads();
  int pos = 0;
  if (act) pos = atomicAdd(&lcnt[g], 1);
  __syncthreads();
  if (tid < 8) lbase[tid] = atomicAdd(&counts[tid], lcnt[tid]);
  if (tid == 0)
    lens[b] = lcnt[0] + lcnt[1] + lcnt[2] + lcnt[3] +
              lcnt[4] + lcnt[5] + lcnt[6] + lcnt[7];
  __syncthreads();
  if (act) idxbuf[g * 32768 + lbase[g] + pos] = n;
}

// Base embedding: shank_emb[sid] + positional encoding.
__global__ __launch_bounds__(256) void init_emb_kernel(
    const int* __restrict__ sid, const float* __restrict__ shank_emb,
    float* __restrict__ hout) {
  int i = blockIdx.x * 256 + threadIdx.x;
  int n = i >> 6, e = i & 63, s = n & 255;
  int g = sid[n];
  float div = __expf(-(float)(e & ~1) * (9.21034037f / 64.f));
  float angle = (float)s * div;
  float pe = (e & 1) ? cosf(angle) : sinf(angle);
  hout[i] = shank_emb[g * 64 + e] + pe;
}

// Conv encoder via bf16 MFMA. t-major LDS layouts make each conv tap a
// K-contiguous GEMM term (no im2col duplication).
#define CONV_BPG 64
__global__ __launch_bounds__(256) void conv_mfma_kernel(
    const int* __restrict__ idxbuf, const int* __restrict__ counts,
    const float* __restrict__ wav,
    const float* __restrict__ w1_, const float* __restrict__ b1_,
    const float* __restrict__ w2_, const float* __restrict__ b2_,
    float* __restrict__ hout) {
  __shared__ __align__(16) unsigned short w1f[5][32][8];    // [tap][oc][ic pad8]
  __shared__ __align__(16) unsigned short w2f[3][64][40];   // [tap][e][ic pad40]
  __shared__ float b1s[32];
  __shared__ float b2s[64];
  __shared__ __align__(16) unsigned short xT[8][36][8];     // [tok][tpad][ic pad8]
  __shared__ __align__(16) unsigned short h1T[8][34][40];   // [tok][tpad][oc pad40]
  int g = blockIdx.x & 7, bib = blockIdx.x >> 3;
  int tid = threadIdx.x;
  int wv = tid >> 6, lane = tid & 63, quad = lane >> 4, l15 = lane & 15;
  for (int i = tid; i < 1280; i += 256) {
    int k = i >> 8, rest = i & 255, oc = rest >> 3, ic = rest & 7;
    w1f[k][oc][ic] = (ic < 6) ? f2bf(w1_[g * 960 + oc * 30 + ic * 5 + k]) : 0;
  }
  for (int i = tid; i < 7680; i += 256) {
    int k = i / 2560, rest = i % 2560, e = rest / 40, ic = rest % 40;
    w2f[k][e][ic] = (ic < 32) ? f2bf(w2_[g * 6144 + e * 96 + ic * 3 + k]) : 0;
  }
  if (tid < 32) b1s[tid] = b1_[g * 32 + tid];
  if (tid < 64) b2s[tid] = b2_[g * 64 + tid];
  for (int i = tid; i < 640; i += 256) {
    int tok = i / 80, rest = i % 80;
    h1T[tok][(rest >= 40) ? 33 : 0][rest % 40] = 0;
  }
  __syncthreads();
  bf16x8 zf = {0, 0, 0, 0, 0, 0, 0, 0};
  bf16x8 bf1[2], bf1k4[2], bf2[3][4];
#pragma unroll
  for (int nt = 0; nt < 2; nt++) {
    bf1[nt] = ldfrag(&w1f[quad][nt * 16 + l15][0]);
    bf1k4[nt] = (quad == 0) ? ldfrag(&w1f[4][nt * 16 + l15][0]) : zf;
  }
#pragma unroll
  for (int k = 0; k < 3; k++)
#pragma unroll
    for (int nt = 0; nt < 4; nt++)
      bf2[k][nt] = ldfrag(&w2f[k][nt * 16 + l15][quad * 8]);
  float b1v0 = b1s[l15], b1v1 = b1s[16 + l15];
  int cnt = counts[g];
  for (int base = bib * 8; base < cnt; base += CONV_BPG * 8) {
    __syncthreads();
    for (int i = tid; i < 2304; i += 256) {
      int tok = i / 288, rest = i % 288, row = rest >> 3, ic = rest & 7;
      unsigned short v = 0;
      int ti = base + tok;
      if (ti < cnt && ic < 6 && row >= 2 && row < 34)
        v = f2bf(wav[idxbuf[g * 32768 + ti] * 192 + ic * 32 + (row - 2)]);
      xT[tok][row][ic] = v;
    }
    __syncthreads();
#pragma unroll
    for (int ts = 0; ts < 2; ts++) {
      int tk = wv * 2 + ts;
      f32x4 c1[2][2];
#pragma unroll
      for (int mt = 0; mt < 2; mt++) {
        c1[mt][0] = (f32x4){b1v0, b1v0, b1v0, b1v0};
        c1[mt][1] = (f32x4){b1v1, b1v1, b1v1, b1v1};
      }
#pragma unroll
      for (int mt = 0; mt < 2; mt++) {
        bf16x8 afm = ldfrag(&xT[tk][mt * 16 + l15 + quad][0]);
        bf16x8 af4 = (quad == 0) ? ldfrag(&xT[tk][mt * 16 + l15 + 4][0]) : zf;
#pragma unroll
        for (int nt = 0; nt < 2; nt++) {
          c1[mt][nt] = __builtin_amdgcn_mfma_f32_16x16x32_bf16(afm, bf1[nt], c1[mt][nt], 0, 0, 0);
          c1[mt][nt] = __builtin_amdgcn_mfma_f32_16x16x32_bf16(af4, bf1k4[nt], c1[mt][nt], 0, 0, 0);
        }
      }
#pragma unroll
      for (int mt = 0; mt < 2; mt++)
#pragma unroll
        for (int nt = 0; nt < 2; nt++)
#pragma unroll
          for (int r = 0; r < 4; r++) {
            int t = mt * 16 + quad * 4 + r;
            h1T[tk][t + 1][nt * 16 + l15] = f2bf(fmaxf(c1[mt][nt][r], 0.f));
          }
    }
    __syncthreads();
#pragma unroll
    for (int ts = 0; ts < 2; ts++) {
      int tk = wv * 2 + ts;
      f32x4 c2[2][4];
#pragma unroll
      for (int mt = 0; mt < 2; mt++)
#pragma unroll
        for (int nt = 0; nt < 4; nt++) {
          float bv = b2s[nt * 16 + l15];
          c2[mt][nt] = (f32x4){bv, bv, bv, bv};
        }
#pragma unroll
      for (int k = 0; k < 3; k++)
#pragma unroll
        for (int mt = 0; mt < 2; mt++) {
          bf16x8 af = ldfrag(&h1T[tk][mt * 16 + l15 + k][quad * 8]);
#pragma unroll
          for (int nt = 0; nt < 4; nt++)
            c2[mt][nt] = __builtin_amdgcn_mfma_f32_16x16x32_bf16(af, bf2[k][nt], c2[mt][nt], 0, 0, 0);
        }
      int ti = base + tk;
      float sums[4];
#pragma unroll
      for (int nt = 0; nt < 4; nt++) {
        float s = 0.f;
#pragma unroll
        for (int mt = 0; mt < 2; mt++)
#pragma unroll
          for (int r = 0; r < 4; r++) s += fmaxf(c2[mt][nt][r], 0.f);
        s += __shfl_xor(s, 16);
        s += __shfl_xor(s, 32);
        sums[nt] = s;
      }
      if (ti < cnt && quad == 0) {
        int n = idxbuf[g * 32768 + ti];
#pragma unroll
        for (int nt = 0; nt < 4; nt++)
          hout[n * 64 + nt * 16 + l15] += sums[nt] * (1.f / 32.f);
      }
    }
  }
}

// bf16-MFMA GEMM: out = A[M][K] @ W[N][K]^T + bias.
// mode 0: store to C. mode 1: relu, store to C. mode 2: H = LayerNorm(H + out).
__global__ __launch_bounds__(256) void mfma_gemm_kernel(
    const float* __restrict__ A, const float* __restrict__ W,
    const float* __restrict__ bias, float* __restrict__ C,
    float* __restrict__ H, const float* __restrict__ lng,
    const float* __restrict__ lnb, int K, int N, int mode) {
  __shared__ __align__(16) unsigned short As[64][72];
  __shared__ __align__(16) unsigned short Bs[64][72];
  int m0 = blockIdx.x * 64, c0 = blockIdx.y * 64;
  int tid = threadIdx.x;
  int wv = tid >> 6, lane = tid & 63, quad = lane >> 4, l15 = lane & 15;
  f32x4 acc[4];
#pragma unroll
  for (int nt = 0; nt < 4; nt++) {
    float b = bias[c0 + nt * 16 + l15];
    acc[nt] = (f32x4){b, b, b, b};
  }
  for (int kc = 0; kc < K; kc += 64) {
    __syncthreads();
    for (int i = tid; i < 1024; i += 256) {
      int r = i >> 4, c4 = (i & 15) << 2;
      float4 av = *(const float4*)&A[(size_t)(m0 + r) * K + kc + c4];
      short4 t;
      t.x = (short)f2bf(av.x); t.y = (short)f2bf(av.y);
      t.z = (short)f2bf(av.z); t.w = (short)f2bf(av.w);
      *(short4*)&As[r][c4] = t;
      float4 wv4 = *(const float4*)&W[(size_t)(c0 + r) * K + kc + c4];
      short4 u;
      u.x = (short)f2bf(wv4.x); u.y = (short)f2bf(wv4.y);
      u.z = (short)f2bf(wv4.z); u.w = (short)f2bf(wv4.w);
      *(short4*)&Bs[r][c4] = u;
    }
    __syncthreads();
#pragma unroll
    for (int ks = 0; ks < 64; ks += 32) {
      bf16x8 af = ldfrag(&As[wv * 16 + l15][ks + quad * 8]);
#pragma unroll
      for (int nt = 0; nt < 4; nt++) {
        bf16x8 bfr = ldfrag(&Bs[nt * 16 + l15][ks + quad * 8]);
        acc[nt] = __builtin_amdgcn_mfma_f32_16x16x32_bf16(af, bfr, acc[nt], 0, 0, 0);
      }
    }
  }
  int mrow = m0 + wv * 16 + quad * 4;
  if (mode <= 1) {
#pragma unroll
    for (int nt = 0; nt < 4; nt++)
#pragma unroll
      for (int r = 0; r < 4; r++) {
        float v = acc[nt][r];
        if (mode == 1) v = fmaxf(v, 0.f);
        C[(size_t)(mrow + r) * N + c0 + nt * 16 + l15] = v;
      }
  } else {
#pragma unroll
    for (int r = 0; r < 4; r++) {
      float rv[4];
      float s = 0.f;
#pragma unroll
      for (int nt = 0; nt < 4; nt++) {
        float v = acc[nt][r] + H[(size_t)(mrow + r) * 64 + nt * 16 + l15];
        rv[nt] = v; s += v;
      }
      s += __shfl_xor(s, 1); s += __shfl_xor(s, 2);
      s += __shfl_xor(s, 4); s += __shfl_xor(s, 8);
      float mean = s * (1.f / 64.f);
      float vsum = 0.f;
#pragma unroll
      for (int nt = 0; nt < 4; nt++) { rv[nt] -= mean; vsum += rv[nt] * rv[nt]; }
      vsum += __shfl_xor(vsum, 1); vsum += __shfl_xor(vsum, 2);
      vsum += __shfl_xor(vsum, 4); vsum += __shfl_xor(vsum, 8);
      float inv = rsqrtf(vsum * (1.f / 64.f) + 1e-5f);
#pragma unroll
      for (int nt = 0; nt < 4; nt++) {
        int col = nt * 16 + l15;
        H[(size_t)(mrow + r) * 64 + col] = rv[nt] * inv * lng[col] + lnb[col];
      }
    }
  }
}

// Attention: block = (b, head, q-quarter); thread = (query, key-slice of 4).
__global__ __launch_bounds__(256) void attn_kernel(
    const float* __restrict__ qkv, const int* __restrict__ lens,
    float* __restrict__ o) {
  __shared__ __align__(16) float ks[256][16];
  __shared__ __align__(16) float vs[256][16];
  int bh = blockIdx.x >> 2, qblk = blockIdx.x & 3;
  int b_ = bh >> 2, hd = bh & 3;
  int tid = threadIdx.x;
  int len = lens[b_];
  const float* base = qkv + b_ * 256 * 192;
  for (int i = tid; i < len * 4; i += 256) {
    int s = i >> 2, c = (i & 3) << 2;
    *(float4*)&ks[s][c] = *(const float4*)&base[s * 192 + 64 + hd * 16 + c];
    *(float4*)&vs[s][c] = *(const float4*)&base[s * 192 + 128 + hd * 16 + c];
  }
  __syncthreads();
  int q = qblk * 64 + (tid >> 2), slice = tid & 3;
  float qv[16];
  const float* qp = base + q * 192 + hd * 16;
#pragma unroll
  for (int d = 0; d < 16; d++) qv[d] = qp[d] * 0.25f;
  float m = -1e30f, l = 0.f, acc[16] = {};
  for (int kk = slice; kk < len; kk += 4) {
    float kv[16], vv[16];
#pragma unroll
    for (int c = 0; c < 4; c++) { ld4(&ks[kk][c * 4], &kv[c * 4]); ld4(&vs[kk][c * 4], &vv[c * 4]); }
    float sc = 0.f;
#pragma unroll
    for (int d = 0; d < 16; d++) sc += qv[d] * kv[d];
    float mn = fmaxf(m, sc);
    float al = __expf(m - mn), pp = __expf(sc - mn);
    l = l * al + pp;
#pragma unroll
    for (int d = 0; d < 16; d++) acc[d] = acc[d] * al + pp * vv[d];
    m = mn;
  }
#pragma unroll
  for (int off = 1; off <= 2; off <<= 1) {
    float mo = __shfl_xor(m, off);
    float lo = __shfl_xor(l, off);
    float mn = fmaxf(m, mo);
    float sa = __expf(m - mn), sb = __expf(mo - mn);
    l = l * sa + lo * sb;
#pragma unroll
    for (int d = 0; d < 16; d++) {
      float ao = __shfl_xor(acc[d], off);
      acc[d] = acc[d] * sa + ao * sb;
    }
    m = mn;
  }
  float inv = 1.f / l;
  float* op = o + (b_ * 256 + q) * 64 + hd * 16 + slice * 4;
#pragma unroll
  for (int j = 0; j < 4; j++) op[j] = acc[slice * 4 + j] * inv;
}

// Masked mean pool using per-b active length.
__global__ __launch_bounds__(256) void pool_kernel(
    const float* __restrict__ h, const int* __restrict__ lens,
    float* __restrict__ pooled) {
  __shared__ float ps[4][64];
  int b = blockIdx.x;
  int e = threadIdx.x & 63, sp = threadIdx.x >> 6;
  int len = lens[b];
  float sum = 0.f;
  int send = min(sp * 64 + 64, len);
  for (int s = sp * 64; s < send; s++) sum += h[(b * 256 + s) * 64 + e];
  ps[sp][e] = sum;
  __syncthreads();
  if (sp == 0) {
    float tot = ps[0][e] + ps[1][e] + ps[2][e] + ps[3][e];
    pooled[b * 64 + e] = tot / ((float)len + 1e-8f);
  }
}

// Fused heads: cls(3), mus(6), sigmas(6), d(1) -> 16 outputs per b.
__global__ __launch_bounds__(64) void heads_kernel(
    const float* __restrict__ pooled,
    const float* __restrict__ cls_w1, const float* __restrict__ cls_b1,
    const float* __restrict__ cls_w2, const float* __restrict__ cls_b2,
    const float* __restrict__ mu_w1, const float* __restrict__ mu_b1,
    const float* __restrict__ mu_w2, const float* __restrict__ mu_b2,
    const float* __restrict__ ls_w1, const float* __restrict__ ls_b1,
    const float* __restrict__ ls_w2, const float* __restrict__ ls_b2,
    const float* __restrict__ d_w1, const float* __restrict__ d_b1,
    const float* __restrict__ d_w2, const float* __restrict__ d_b2,
    float* __restrict__ out) {
  int b = blockIdx.x, e = threadIdx.x;
  __shared__ float p[64];
  __shared__ float t1[64];
  p[e] = pooled[b * 64 + e];
  __syncthreads();
  {
    float a = cls_b1[e];
    for (int j = 0; j < 64; j++) a += p[j] * cls_w1[e * 64 + j];
    t1[e] = fmaxf(a, 0.f);
  }
  __syncthreads();
  if (e < 3) {
    float a2 = cls_b2[e];
    for (int j = 0; j < 64; j++) a2 += t1[j] * cls_w2[e * 64 + j];
    out[b * 16 + e] = a2;
  }
  for (int z = 0; z < 3; z++) {
    __syncthreads();
    {
      float a = mu_b1[z * 64 + e];
      for (int j = 0; j < 64; j++) a += p[j] * mu_w1[(z * 64 + e) * 64 + j];
      t1[e] = fmaxf(a, 0.f);
    }
    __syncthreads();
    if (e < 2) {
      float a2 = mu_b2[z * 2 + e];
      for (int j = 0; j < 64; j++) a2 += t1[j] * mu_w2[(z * 2 + e) * 64 + j];
      out[b * 16 + 3 + z * 2 + e] = a2;
    }
    __syncthreads();
    {
      float a = ls_b1[z * 64 + e];
      for (int j = 0; j < 64; j++) a += p[j] * ls_w1[(z * 64 + e) * 64 + j];
      t1[e] = fmaxf(a, 0.f);
    }
    __syncthreads();
    if (e < 2) {
      float a2 = ls_b2[z * 2 + e];
      for (int j = 0; j < 64; j++) a2 += t1[j] * ls_w2[(z * 2 + e) * 64 + j];
      out[b * 16 + 9 + z * 2 + e] = __expf(a2);
    }
  }
  __syncthreads();
  {
    float a = d_b1[e];
    for (int j = 0; j < 64; j++) a += p[j] * d_w1[e * 64 + j];
    t1[e] = fmaxf(a, 0.f);
  }
  __syncthreads();
  if (e == 0) {
    float a2 = d_b2[0];
    for (int j = 0; j < 64; j++) a2 += t1[j] * d_w2[j];
    out[b * 16 + 15] = 1.f / (1.f + __expf(-a2));
  }
}

extern "C" void kernel_launch(void* const* d_in, const int* in_sizes, int n_in,
                              void* d_out, int out_size, void* d_ws, size_t ws_size,
                              hipStream_t stream) {
  const float* wav       = (const float*)d_in[0];
  const int*   sid       = (const int*)d_in[1];
  const void*  mask      = d_in[2];
  const float* conv1_w   = (const float*)d_in[3];
  const float* conv1_b   = (const float*)d_in[4];
  const float* conv2_w   = (const float*)d_in[5];
  const float* conv2_b   = (const float*)d_in[6];
  const float* shank_emb = (const float*)d_in[7];
  const float* in_proj_w = (const float*)d_in[8];
  const float* in_proj_b = (const float*)d_in[9];
  const float* out_proj_w= (const float*)d_in[10];
  const float* out_proj_b= (const float*)d_in[11];
  const float* ln1_g     = (const float*)d_in[12];
  const float* ln1_b     = (const float*)d_in[13];
  const float* ff1_w     = (const float*)d_in[14];
  const float* ff1_b     = (const float*)d_in[15];
  const float* ff2_w     = (const float*)d_in[16];
  const float* ff2_b     = (const float*)d_in[17];
  const float* ln2_g     = (const float*)d_in[18];
  const float* ln2_b     = (const float*)d_in[19];
  const float* cls_w1    = (const float*)d_in[20];
  const float* cls_b1    = (const float*)d_in[21];
  const float* cls_w2    = (const float*)d_in[22];
  const float* cls_b2    = (const float*)d_in[23];
  const float* mu_w1     = (const float*)d_in[24];
  const float* mu_b1     = (const float*)d_in[25];
  const float* mu_w2     = (const float*)d_in[26];
  const float* mu_b2     = (const float*)d_in[27];
  const float* ls_w1     = (const float*)d_in[28];
  const float* ls_b1     = (const float*)d_in[29];
  const float* ls_w2     = (const float*)d_in[30];
  const float* ls_b2     = (const float*)d_in[31];
  const float* d_w1      = (const float*)d_in[32];
  const float* d_b1      = (const float*)d_in[33];
  const float* d_w2      = (const float*)d_in[34];
  const float* d_b2      = (const float*)d_in[35];
  float* out = (float*)d_out;

  float* ws = (float*)d_ws;
  float* h      = ws;                    // [32768,64]
  float* qkv    = ws + 2097152;          // [32768,192]
  float* obuf   = ws + 8388608;          // [32768,64] attn out
  float* ff     = ws + 2097152;          // [32768,256] aliases qkv+obuf (dead by ff1)
  float* pooled = ws + 10485760;         // [128,64]
  int*   ip     = (int*)(ws + 10493952);
  int*   flag   = ip;
  int*   counts = ip + 8;
  int*   lens   = ip + 16;               // [128]
  int*   idxbuf = ip + 144;              // [8][32768]

  detect_mask_kernel<<<1, 256, 0, stream>>>((const unsigned int*)mask, flag, counts, lens);
  bin_kernel<<<128, 256, 0, stream>>>(sid, mask, flag, counts, lens, idxbuf);
  init_emb_kernel<<<8192, 256, 0, stream>>>(sid, shank_emb, h);
  conv_mfma_kernel<<<CONV_BPG * 8, 256, 0, stream>>>(idxbuf, counts, wav, conv1_w, conv1_b,
                                                     conv2_w, conv2_b, h);
  for (int l = 0; l < 2; l++) {
    mfma_gemm_kernel<<<dim3(512, 3), 256, 0, stream>>>(
        h, in_proj_w + l * 12288, in_proj_b + l * 192, qkv, h, ln1_g, ln1_b, 64, 192, 0);
    attn_kernel<<<2048, 256, 0, stream>>>(qkv, lens, obuf);
    mfma_gemm_kernel<<<dim3(512, 1), 256, 0, stream>>>(
        obuf, out_proj_w + l * 4096, out_proj_b + l * 64, obuf, h,
        ln1_g + l * 64, ln1_b + l * 64, 64, 64, 2);
    mfma_gemm_kernel<<<dim3(512, 4), 256, 0, stream>>>(
        h, ff1_w + l * 16384, ff1_b + l * 256, ff, h, ln2_g, ln2_b, 64, 256, 1);
    mfma_gemm_kernel<<<dim3(512, 1), 256, 0, stream>>>(
        ff, ff2_w + l * 16384, ff2_b + l * 64, ff, h,
        ln2_g + l * 64, ln2_b + l * 64, 256, 64, 2);
  }
  pool_kernel<<<128, 256, 0, stream>>>(h, lens, pooled);
  heads_kernel<<<128, 64, 0, stream>>>(pooled, cls_w1, cls_b1, cls_w2, cls_b2,
                                       mu_w1, mu_b1, mu_w2, mu_b2,
                                       ls_w1, ls_b1, ls_w2, ls_b2,
                                       d_w1, d_b1, d_w2, d_b2, out);
}